// Round 1
// baseline (320.473 us; speedup 1.0000x reference)
//
#include <hip/hip_runtime.h>

// Problem dims
#define SS 96     // spatial
#define CC 32     // latent
#define TT 16     // time
#define BP 16     // B*P
#define MM 3072   // SS*CC (flattened (e,c) with m = e*32 + c, matching Q/K/V layout [S][S][C])
#define MC 12     // m-chunks in main kernel
#define CHW 256   // chunk width = MM/MC

// ---------------------------------------------------------------------------
// K0a: transpose x[bp,t][c][e] -> xr[bp,t][m] with m = e*32 + c
// so that main-kernel loads of xr are coalesced in m (same layout as Q/K rows).
__global__ __launch_bounds__(256) void k_transpose(const float* __restrict__ x,
                                                   float* __restrict__ xr) {
    __shared__ float lds[SS * 33];  // [e][c] padded stride 33 -> conflict-free
    const int slab = blockIdx.x;    // bp*16 + t, 256 slabs
    const float* xin = x + (size_t)slab * MM;
    float* xout = xr + (size_t)slab * MM;
    for (int i = threadIdx.x; i < MM; i += 256) {
        int c = i / SS, e = i - c * SS;     // input layout [c][e]
        lds[e * 33 + c] = xin[i];
    }
    __syncthreads();
    for (int i = threadIdx.x; i < MM; i += 256) {
        int e = i >> 5, c = i & 31;         // output layout m = e*32 + c
        xout[i] = lds[e * 33 + c];
    }
}

// ---------------------------------------------------------------------------
// K0b: WA[X][x][t] = w[x] * Aoo[X][x][t]   (147456 elements)
__global__ __launch_bounds__(256) void k_wa(const float* __restrict__ Aoo,
                                            const float* __restrict__ w,
                                            float* __restrict__ wa) {
    int idx = blockIdx.x * 256 + threadIdx.x;   // 576 blocks * 256 = 147456 exactly
    int xx = (idx >> 4) % SS;
    wa[idx] = w[xx] * Aoo[idx];
}

// ---------------------------------------------------------------------------
// K1: fused P + g.
//   P[X,t,m]  = sum_x WA[X,x,t] * Q[x,m]          (never materialized)
//   g[bp,X]  += sum_t P[X,t,m] * K[X,m] * xr[bp,t,m]
// grid (X=96, mc=12), 256 threads; each thread owns one m = mc*256 + tid.
__global__ __launch_bounds__(256) void k_main(const float* __restrict__ Q,
                                              const float* __restrict__ K,
                                              const float* __restrict__ xr,
                                              const float* __restrict__ wa,
                                              float* __restrict__ gpart) {
    const int X = blockIdx.x;
    const int mc = blockIdx.y;
    const int m = mc * CHW + threadIdx.x;

    const float* wap = wa + X * (SS * TT);   // wave-uniform address -> scalar loads
    const float* Qp = Q + m;

    float pk[TT];
#pragma unroll
    for (int t = 0; t < TT; ++t) pk[t] = 0.f;

    for (int xx = 0; xx < SS; ++xx) {
        float qv = Qp[xx * MM];              // coalesced, L2-resident
        const float* wrow = wap + xx * TT;   // uniform
#pragma unroll
        for (int t = 0; t < TT; ++t) pk[t] = fmaf(wrow[t], qv, pk[t]);
    }

    const float kv = K[X * MM + m];
#pragma unroll
    for (int t = 0; t < TT; ++t) pk[t] *= kv;

    float g[BP];
#pragma unroll
    for (int b = 0; b < BP; ++b) {
        const float* xp = xr + (size_t)b * (TT * MM) + m;
        float acc = 0.f;
#pragma unroll
        for (int t = 0; t < TT; ++t) acc = fmaf(pk[t], xp[t * MM], acc);
        g[b] = acc;
    }

    // reduce g over the 256 threads of the block
#pragma unroll
    for (int b = 0; b < BP; ++b) {
        float v = g[b];
        v += __shfl_down(v, 32, 64);
        v += __shfl_down(v, 16, 64);
        v += __shfl_down(v, 8, 64);
        v += __shfl_down(v, 4, 64);
        v += __shfl_down(v, 2, 64);
        v += __shfl_down(v, 1, 64);
        g[b] = v;
    }
    __shared__ float wred[4 * BP];
    const int lane = threadIdx.x & 63, wid = threadIdx.x >> 6;
    if (lane == 0) {
#pragma unroll
        for (int b = 0; b < BP; ++b) wred[wid * BP + b] = g[b];
    }
    __syncthreads();
    if (threadIdx.x < BP) {
        float v = wred[threadIdx.x] + wred[BP + threadIdx.x] +
                  wred[2 * BP + threadIdx.x] + wred[3 * BP + threadIdx.x];
        gpart[(X * MC + mc) * BP + threadIdx.x] = v;
    }
}

// ---------------------------------------------------------------------------
// K2: q[bp,c,X] = sum_e V[X,e,c] * x[bp, T-1, c, e];  y[bp,c] = sum_X q * G[bp,X]
// grid = 16 blocks (one per bp), 256 threads: thread = (grp = tid>>5, c = tid&31)
__global__ __launch_bounds__(256) void k_final(const float* __restrict__ x,
                                               const float* __restrict__ V,
                                               const float* __restrict__ gpart,
                                               float* __restrict__ y) {
    const int bp = blockIdx.x;
    __shared__ float xl[SS * 33];   // xl[e*33+c] = x[bp,T-1,c,e], conflict-free
    __shared__ float G[SS];
    __shared__ float red[8 * CC];

    const float* xs = x + (size_t)bp * (TT * MM) + (TT - 1) * MM;
    for (int i = threadIdx.x; i < MM; i += 256) {
        int c = i / SS, e = i - c * SS;
        xl[e * 33 + c] = xs[i];
    }
    if (threadIdx.x < SS) {
        float v = 0.f;
#pragma unroll
        for (int mc2 = 0; mc2 < MC; ++mc2)
            v += gpart[(threadIdx.x * MC + mc2) * BP + bp];
        G[threadIdx.x] = v;
    }
    __syncthreads();

    const int c = threadIdx.x & 31;
    const int grp = threadIdx.x >> 5;   // 0..7
    float yacc = 0.f;
    for (int k = 0; k < 12; ++k) {
        int X = grp * 12 + k;
        const float* Vp = V + X * MM + c;
        float q = 0.f;
        for (int e = 0; e < SS; ++e) q = fmaf(Vp[e * CC], xl[e * 33 + c], q);
        yacc = fmaf(q, G[X], yacc);
    }
    red[grp * CC + c] = yacc;
    __syncthreads();
    if (threadIdx.x < CC) {
        float v = 0.f;
#pragma unroll
        for (int gg = 0; gg < 8; ++gg) v += red[gg * CC + threadIdx.x];
        y[bp * CC + threadIdx.x] = v;   // output [B,P,1,C] flat = bp*32 + c
    }
}

// ---------------------------------------------------------------------------
extern "C" void kernel_launch(void* const* d_in, const int* in_sizes, int n_in,
                              void* d_out, int out_size, void* d_ws, size_t ws_size,
                              hipStream_t stream) {
    const float* x   = (const float*)d_in[0];
    const float* Q   = (const float*)d_in[1];
    const float* K   = (const float*)d_in[2];
    const float* V   = (const float*)d_in[3];
    const float* Aoo = (const float*)d_in[4];
    const float* w   = (const float*)d_in[5];

    float* ws = (float*)d_ws;
    float* xr    = ws;                        // 786432 floats (3.0 MB)
    float* wa    = ws + 786432;               // 147456 floats (0.56 MB)
    float* gpart = ws + 786432 + 147456;      // 96*12*16 = 18432 floats
    // total ws need: 3,809,280 bytes

    k_transpose<<<dim3(BP * TT), 256, 0, stream>>>(x, xr);
    k_wa<<<dim3(576), 256, 0, stream>>>(Aoo, w, wa);
    k_main<<<dim3(SS, MC), 256, 0, stream>>>(Q, K, xr, wa, gpart);
    k_final<<<dim3(BP), 256, 0, stream>>>(x, V, gpart, (float*)d_out);
}

// Round 2
// 60.882 us; speedup vs baseline: 5.2638x; 5.2638x over previous
//
#include <hip/hip_runtime.h>

// Problem dims
#define SS 96     // spatial
#define CC 32     // latent
#define TT 16     // time
#define BP 16     // B*P
#define MM 3072   // SS*CC (flattened (e,c) with m = e*32 + c, matching Q/K/V layout [S][S][C])
#define MC 12     // m-chunks in main kernel
#define CHW 256   // chunk width = MM/MC

// ---------------------------------------------------------------------------
// K0a: transpose x[bp,t][c][e] -> xr[bp,t][m] with m = e*32 + c
__global__ __launch_bounds__(256) void k_transpose(const float* __restrict__ x,
                                                   float* __restrict__ xr) {
    __shared__ float lds[SS * 33];  // [e][c] padded stride 33 -> conflict-free
    const int slab = blockIdx.x;    // bp*16 + t, 256 slabs
    const float* xin = x + (size_t)slab * MM;
    float* xout = xr + (size_t)slab * MM;
    for (int i = threadIdx.x; i < MM; i += 256) {
        int c = i / SS, e = i - c * SS;     // input layout [c][e]
        lds[e * 33 + c] = xin[i];
    }
    __syncthreads();
    for (int i = threadIdx.x; i < MM; i += 256) {
        int e = i >> 5, c = i & 31;         // output layout m = e*32 + c
        xout[i] = lds[e * 33 + c];
    }
}

// ---------------------------------------------------------------------------
// K0b: WA[X][x][t] = w[x] * Aoo[X][x][t]   (147456 elements)
__global__ __launch_bounds__(256) void k_wa(const float* __restrict__ Aoo,
                                            const float* __restrict__ w,
                                            float* __restrict__ wa) {
    int idx = blockIdx.x * 256 + threadIdx.x;   // 576 blocks * 256 = 147456 exactly
    int xx = (idx >> 4) % SS;
    wa[idx] = w[xx] * Aoo[idx];
}

// ---------------------------------------------------------------------------
// K1: fused P + g.
//   P[X,t,m]  = sum_x WA[X,x,t] * Q[x,m]          (never materialized)
//   g[bp,X]  += sum_t P[X,t,m] * K[X,m] * xr[bp,t,m]
__global__ __launch_bounds__(256) void k_main(const float* __restrict__ Q,
                                              const float* __restrict__ K,
                                              const float* __restrict__ xr,
                                              const float* __restrict__ wa,
                                              float* __restrict__ gpart) {
    const int X = blockIdx.x;
    const int mc = blockIdx.y;
    const int m = mc * CHW + threadIdx.x;

    const float* wap = wa + X * (SS * TT);   // wave-uniform address -> scalar loads
    const float* Qp = Q + m;

    float pk[TT];
#pragma unroll
    for (int t = 0; t < TT; ++t) pk[t] = 0.f;

    for (int xx = 0; xx < SS; ++xx) {
        float qv = Qp[xx * MM];              // coalesced, L2-resident
        const float* wrow = wap + xx * TT;   // uniform
#pragma unroll
        for (int t = 0; t < TT; ++t) pk[t] = fmaf(wrow[t], qv, pk[t]);
    }

    const float kv = K[X * MM + m];
#pragma unroll
    for (int t = 0; t < TT; ++t) pk[t] *= kv;

    float g[BP];
#pragma unroll
    for (int b = 0; b < BP; ++b) {
        const float* xp = xr + (size_t)b * (TT * MM) + m;
        float acc = 0.f;
#pragma unroll
        for (int t = 0; t < TT; ++t) acc = fmaf(pk[t], xp[t * MM], acc);
        g[b] = acc;
    }

    // reduce g over the 256 threads of the block
#pragma unroll
    for (int b = 0; b < BP; ++b) {
        float v = g[b];
        v += __shfl_down(v, 32, 64);
        v += __shfl_down(v, 16, 64);
        v += __shfl_down(v, 8, 64);
        v += __shfl_down(v, 4, 64);
        v += __shfl_down(v, 2, 64);
        v += __shfl_down(v, 1, 64);
        g[b] = v;
    }
    __shared__ float wred[4 * BP];
    const int lane = threadIdx.x & 63, wid = threadIdx.x >> 6;
    if (lane == 0) {
#pragma unroll
        for (int b = 0; b < BP; ++b) wred[wid * BP + b] = g[b];
    }
    __syncthreads();
    if (threadIdx.x < BP) {
        float v = wred[threadIdx.x] + wred[BP + threadIdx.x] +
                  wred[2 * BP + threadIdx.x] + wred[3 * BP + threadIdx.x];
        gpart[(X * MC + mc) * BP + threadIdx.x] = v;
    }
}

// ---------------------------------------------------------------------------
// K2a: G[X*16+bp] = sum_mc gpart[(X*12+mc)*16+bp]   (1536 values)
__global__ __launch_bounds__(256) void k_gred(const float* __restrict__ gpart,
                                              float* __restrict__ G) {
    int idx = blockIdx.x * 256 + threadIdx.x;   // 6*256 = 1536 exactly
    float v = 0.f;
#pragma unroll
    for (int mc = 0; mc < MC; ++mc) v += gpart[((idx >> 4) * MC + mc) * BP + (idx & 15)];
    G[idx] = v;
}

// ---------------------------------------------------------------------------
// K2b: ypart[xc,bp,c] = sum_{X in chunk xc} G[bp,X] * sum_e V[X,e,c]*x[bp,T-1,c,e]
// grid (bp=16, xc=12), 256 threads = (grp=tid>>5 -> X = xc*8+grp, c = tid&31)
__global__ __launch_bounds__(256) void k_y(const float* __restrict__ x,
                                           const float* __restrict__ V,
                                           const float* __restrict__ G,
                                           float* __restrict__ ypart) {
    const int bp = blockIdx.x;
    const int xc = blockIdx.y;
    __shared__ float xl[SS * 33];   // xl[e*33+c] = x[bp,T-1,c,e] (conflict-free)
    __shared__ float red[8 * CC];

    const float* xs = x + (size_t)bp * (TT * MM) + (TT - 1) * MM;
    for (int i = threadIdx.x; i < MM; i += 256) {
        int c = i / SS, e = i - c * SS;
        xl[e * 33 + c] = xs[i];
    }
    __syncthreads();

    const int c = threadIdx.x & 31;
    const int grp = threadIdx.x >> 5;       // 0..7
    const int X = xc * 8 + grp;
    const float* Vp = V + (size_t)X * MM + c;   // coalesced across c lanes
    float acc = 0.f;
#pragma unroll 8
    for (int e = 0; e < SS; ++e)
        acc = fmaf(Vp[e * CC], xl[e * 33 + c], acc);
    acc *= G[X * BP + bp];

    red[grp * CC + c] = acc;
    __syncthreads();
    if (threadIdx.x < CC) {
        float v = 0.f;
#pragma unroll
        for (int g = 0; g < 8; ++g) v += red[g * CC + threadIdx.x];
        ypart[(xc * BP + bp) * CC + threadIdx.x] = v;
    }
}

// ---------------------------------------------------------------------------
// K2c: y[bp,c] = sum_xc ypart[xc,bp,c]   (512 outputs)
__global__ __launch_bounds__(512) void k_ysum(const float* __restrict__ ypart,
                                              float* __restrict__ y) {
    const int i = threadIdx.x;   // 512 = BP*CC
    float v = 0.f;
#pragma unroll
    for (int xc = 0; xc < MC; ++xc) v += ypart[xc * (BP * CC) + i];
    y[i] = v;
}

// ---------------------------------------------------------------------------
extern "C" void kernel_launch(void* const* d_in, const int* in_sizes, int n_in,
                              void* d_out, int out_size, void* d_ws, size_t ws_size,
                              hipStream_t stream) {
    const float* x   = (const float*)d_in[0];
    const float* Q   = (const float*)d_in[1];
    const float* K   = (const float*)d_in[2];
    const float* V   = (const float*)d_in[3];
    const float* Aoo = (const float*)d_in[4];
    const float* w   = (const float*)d_in[5];

    float* ws = (float*)d_ws;
    float* xr    = ws;                                  // 786432 floats
    float* wa    = ws + 786432;                         // 147456 floats
    float* gpart = ws + 786432 + 147456;                // 18432 floats
    float* G     = ws + 786432 + 147456 + 18432;        // 1536 floats
    float* ypart = ws + 786432 + 147456 + 18432 + 1536; // 6144 floats
    // total ws need: 960,000 floats = 3.84 MB

    k_transpose<<<dim3(BP * TT), 256, 0, stream>>>(x, xr);
    k_wa<<<dim3(576), 256, 0, stream>>>(Aoo, w, wa);
    k_main<<<dim3(SS, MC), 256, 0, stream>>>(Q, K, xr, wa, gpart);
    k_gred<<<dim3(6), 256, 0, stream>>>(gpart, G);
    k_y<<<dim3(BP, MC), 256, 0, stream>>>(x, V, G, ypart);
    k_ysum<<<dim3(1), 512, 0, stream>>>(ypart, (float*)d_out);
}

// Round 3
// 55.099 us; speedup vs baseline: 5.8163x; 1.1050x over previous
//
#include <hip/hip_runtime.h>

// Problem dims
#define SS 96     // spatial
#define CC 32     // latent
#define TT 16     // time
#define BP 16     // B*P
#define MM 3072   // SS*CC (flattened (e,c), m = e*32 + c, matches Q/K/V row layout [S][S][C])
#define MC 12     // m-chunks in main kernel
#define CHW 256   // chunk width = MM/MC

// ---------------------------------------------------------------------------
// K1: prep (grid 840):
//   blocks [0,256):   transpose x[bp,t][c][e] -> xr[bp,t][m], m = e*32+c
//   blocks [256,832): WA2[u][v][t] = w[v] * Aoo[v][u][t]   (147456 elements)
//   blocks [832,840): zero G (1536) and y (512)
__global__ __launch_bounds__(256) void k_prep(const float* __restrict__ x,
                                              const float* __restrict__ Aoo,
                                              const float* __restrict__ w,
                                              float* __restrict__ xr,
                                              float* __restrict__ wa,
                                              float* __restrict__ G,
                                              float* __restrict__ y) {
    __shared__ float lds[SS * 33];
    const int bid = blockIdx.x;
    if (bid < 256) {
        const float* xin = x + (size_t)bid * MM;
        float* xout = xr + (size_t)bid * MM;
        for (int i = threadIdx.x; i < MM; i += 256) {
            int c = i / SS, e = i - c * SS;   // input layout [c][e]
            lds[e * 33 + c] = xin[i];
        }
        __syncthreads();
        for (int i = threadIdx.x; i < MM; i += 256) {
            int e = i >> 5, c = i & 31;       // output m = e*32 + c
            xout[i] = lds[e * 33 + c];
        }
    } else if (bid < 832) {
        int idx = (bid - 256) * 256 + threadIdx.x;  // 0..147455 = u*1536 + v*16 + t
        int u = idx / (SS * TT);
        int v = (idx >> 4) % SS;
        int t = idx & 15;
        wa[idx] = w[v] * Aoo[(v * SS + u) * TT + t];
    } else {
        int i = (bid - 832) * 256 + threadIdx.x;    // 0..2047
        if (i < 1536) G[i] = 0.f;
        else if (i < 1536 + BP * CC) y[i - 1536] = 0.f;
    }
}

// ---------------------------------------------------------------------------
// K2: fused P + g.
//   P[X,t,m]  = sum_v WA2[X,v,t] * Q[v,m]          (never materialized)
//   G[X,b]   += sum_t P[X,t,m] * K[X,m] * xr[b,t,m]   (atomic over m-chunks)
__global__ __launch_bounds__(256) void k_main(const float* __restrict__ Q,
                                              const float* __restrict__ K,
                                              const float* __restrict__ xr,
                                              const float* __restrict__ wa,
                                              float* __restrict__ G) {
    const int X = blockIdx.x;
    const int mc = blockIdx.y;
    const int m = mc * CHW + threadIdx.x;

    const float* wap = wa + X * (SS * TT);   // wave-uniform address -> scalar loads
    const float* Qp = Q + m;

    float pk[TT];
#pragma unroll
    for (int t = 0; t < TT; ++t) pk[t] = 0.f;

    for (int v = 0; v < SS; ++v) {
        float qv = Qp[v * MM];               // coalesced, L2-resident
        const float* wrow = wap + v * TT;    // uniform
#pragma unroll
        for (int t = 0; t < TT; ++t) pk[t] = fmaf(wrow[t], qv, pk[t]);
    }

    const float kv = K[X * MM + m];
#pragma unroll
    for (int t = 0; t < TT; ++t) pk[t] *= kv;

    float g[BP];
#pragma unroll
    for (int b = 0; b < BP; ++b) {
        const float* xp = xr + (size_t)b * (TT * MM) + m;
        float acc = 0.f;
#pragma unroll
        for (int t = 0; t < TT; ++t) acc = fmaf(pk[t], xp[t * MM], acc);
        g[b] = acc;
    }

    // reduce g over the 256 threads of the block, then one atomic per (X,b)
#pragma unroll
    for (int b = 0; b < BP; ++b) {
        float v = g[b];
        v += __shfl_down(v, 32, 64);
        v += __shfl_down(v, 16, 64);
        v += __shfl_down(v, 8, 64);
        v += __shfl_down(v, 4, 64);
        v += __shfl_down(v, 2, 64);
        v += __shfl_down(v, 1, 64);
        g[b] = v;
    }
    __shared__ float wred[4 * BP];
    const int lane = threadIdx.x & 63, wid = threadIdx.x >> 6;
    if (lane == 0) {
#pragma unroll
        for (int b = 0; b < BP; ++b) wred[wid * BP + b] = g[b];
    }
    __syncthreads();
    if (threadIdx.x < BP) {
        float v = wred[threadIdx.x] + wred[BP + threadIdx.x] +
                  wred[2 * BP + threadIdx.x] + wred[3 * BP + threadIdx.x];
        atomicAdd(&G[X * BP + threadIdx.x], v);
    }
}

// ---------------------------------------------------------------------------
// K3: y[bp,c] += sum_{X in chunk xc} G[X,bp] * sum_e V[X,e,c]*x[bp,T-1,c,e]
// grid (bp=16, xc=12), 256 threads = (grp=tid>>5 -> X = xc*8+grp, c = tid&31)
__global__ __launch_bounds__(256) void k_y(const float* __restrict__ x,
                                           const float* __restrict__ V,
                                           const float* __restrict__ G,
                                           float* __restrict__ y) {
    const int bp = blockIdx.x;
    const int xc = blockIdx.y;
    __shared__ float xl[SS * 33];   // xl[e*33+c] = x[bp,T-1,c,e] (conflict-free)
    __shared__ float red[8 * CC];

    const float* xs = x + (size_t)bp * (TT * MM) + (TT - 1) * MM;
    for (int i = threadIdx.x; i < MM; i += 256) {
        int c = i / SS, e = i - c * SS;
        xl[e * 33 + c] = xs[i];
    }
    __syncthreads();

    const int c = threadIdx.x & 31;
    const int grp = threadIdx.x >> 5;       // 0..7
    const int X = xc * 8 + grp;
    const float* Vp = V + (size_t)X * MM + c;   // coalesced across c lanes
    float acc = 0.f;
#pragma unroll 8
    for (int e = 0; e < SS; ++e)
        acc = fmaf(Vp[e * CC], xl[e * 33 + c], acc);
    acc *= G[X * BP + bp];

    red[grp * CC + c] = acc;
    __syncthreads();
    if (threadIdx.x < CC) {
        float v = 0.f;
#pragma unroll
        for (int g = 0; g < 8; ++g) v += red[g * CC + threadIdx.x];
        atomicAdd(&y[bp * CC + threadIdx.x], v);
    }
}

// ---------------------------------------------------------------------------
extern "C" void kernel_launch(void* const* d_in, const int* in_sizes, int n_in,
                              void* d_out, int out_size, void* d_ws, size_t ws_size,
                              hipStream_t stream) {
    const float* x   = (const float*)d_in[0];
    const float* Q   = (const float*)d_in[1];
    const float* K   = (const float*)d_in[2];
    const float* V   = (const float*)d_in[3];
    const float* Aoo = (const float*)d_in[4];
    const float* w   = (const float*)d_in[5];

    float* ws = (float*)d_ws;
    float* xr = ws;                        // 786432 floats
    float* wa = ws + 786432;               // 147456 floats
    float* G  = ws + 786432 + 147456;      // 1536 floats
    // total ws need: ~3.75 MB

    float* y = (float*)d_out;

    k_prep<<<dim3(840), 256, 0, stream>>>(x, Aoo, w, xr, wa, G, y);
    k_main<<<dim3(SS, MC), 256, 0, stream>>>(Q, K, xr, wa, G);
    k_y<<<dim3(BP, MC), 256, 0, stream>>>(x, V, G, y);
}